// Round 6
// baseline (102.624 us; speedup 1.0000x reference)
//
#include <hip/hip_runtime.h>
#include <cstdint>

// DIAGNOSTIC ROUND: R5 kernel x K=20 internal repeats so the dispatch exceeds the
// 40us fillBuffer dispatches and our counters appear in top-5. Each iteration does
// the complete fresh computation (same output); asm pointer-laundering defeats
// loop-invariant hoisting. Revert to K=1 next round.
#define LOG2E 1.4426950408889634f
#define LN2   0.6931471805599453f
#define KREP  20

__global__ __launch_bounds__(256) void fused_lse(const float* __restrict__ ll_in,
                                                 const float* __restrict__ logits_in,
                                                 float* __restrict__ out_in) {
    __shared__ float S[8928];
    float* Wb = S;
    float* Eb = S + 4288;
    float* T2 = S + 4288;                    // reuse of Eb region after barrier 2

    const int t = threadIdx.x;
    const int w = t >> 6;                    // wave 0..3
    const int l = t & 63;

    const int bid = (int)blockIdx.x;
    const int swz = ((bid & 7) << 7) + (bid >> 3);
    const int f   = swz >> 4;
    const int b0  = (swz & 15) << 4;

    const float* ll     = ll_in;
    const float* logits = logits_in;
    float*       out    = out_in;

    for (int it = 0; it < KREP; ++it) {
        // launder pointers so the compiler cannot hoist loads/compute out of the loop
        asm volatile("" : "+v"(ll), "+v"(logits), "+v"(out));

        // ---- A1: cold ll loads first (4 x float4 per thread) ----
        float4 v[4];
        const float* llb = ll + (((size_t)b0 * 64 + f) << 8) + l * 4;
        #pragma unroll
        for (int j = 0; j < 4; ++j) {
            const int row = j * 4 + w;       // 0..15, wave-uniform
            v[j] = *(const float4*)(llb + ((size_t)row << 14));
        }

        // ---- A2: logits loads for softmax (threads 0..127) ----
        float x[32];
        if (t < 128) {
            const float* lg = logits + ((size_t)f << 12) + t;
            #pragma unroll
            for (int c = 0; c < 32; ++c) x[c] = lg[c << 7];
        }

        // ---- A3: exp(ll) -> Eb[r*580 + row*36 + cin] ----
        {
            const int cin = l >> 1;
            const int r0  = (l & 1) << 2;
            #pragma unroll
            for (int j = 0; j < 4; ++j) {
                const int row = j * 4 + w;
                float* eb = Eb + row * 36 + cin;
                eb[(r0 + 0) * 580] = __builtin_amdgcn_exp2f(v[j].x * LOG2E);
                eb[(r0 + 1) * 580] = __builtin_amdgcn_exp2f(v[j].y * LOG2E);
                eb[(r0 + 2) * 580] = __builtin_amdgcn_exp2f(v[j].z * LOG2E);
                eb[(r0 + 3) * 580] = __builtin_amdgcn_exp2f(v[j].w * LOG2E);
            }
        }

        // ---- A4: softmax over cin -> Wb[(r*2+coH)*268 + coL + cin*8] ----
        if (t < 128) {
            const int r_  = t & 7;
            const int coH = t >> 6;
            const int coL = (t >> 3) & 7;
            float m = x[0];
            #pragma unroll
            for (int c = 1; c < 32; ++c) m = fmaxf(m, x[c]);
            float s = 0.f;
            #pragma unroll
            for (int c = 0; c < 32; ++c) { x[c] = __builtin_amdgcn_exp2f((x[c] - m) * LOG2E); s += x[c]; }
            const float inv = 1.0f / s;
            float* wrow = Wb + ((r_ << 1) + coH) * 268 + coL;
            #pragma unroll
            for (int c = 0; c < 32; ++c) wrow[c * 8] = x[c] * inv;
        }
        __syncthreads();

        // ---- C: acc[cout8] = sum_cin E[b][cin] * W[cin][cout] ----
        const int r  = (w << 1) + (l >> 5);
        const int ch = (l >> 4) & 1;
        const int b  = l & 15;

        float4 e4[8];
        const float* Ew = Eb + r * 580 + b * 36;
        #pragma unroll
        for (int q = 0; q < 8; ++q) e4[q] = *(const float4*)&Ew[q * 4];

        const float* Ww = Wb + ((r << 1) + ch) * 268;
        float acc[8] = {0.f, 0.f, 0.f, 0.f, 0.f, 0.f, 0.f, 0.f};
        #pragma unroll
        for (int cc = 0; cc < 8; ++cc) {
            #pragma unroll
            for (int i = 0; i < 4; ++i) {
                const float  ev = (i == 0) ? e4[cc].x : (i == 1) ? e4[cc].y : (i == 2) ? e4[cc].z : e4[cc].w;
                const float4 wa = *(const float4*)&Ww[(cc * 4 + i) * 8];
                const float4 wc = *(const float4*)&Ww[(cc * 4 + i) * 8 + 4];
                acc[0] = fmaf(ev, wa.x, acc[0]);
                acc[1] = fmaf(ev, wa.y, acc[1]);
                acc[2] = fmaf(ev, wa.z, acc[2]);
                acc[3] = fmaf(ev, wa.w, acc[3]);
                acc[4] = fmaf(ev, wc.x, acc[4]);
                acc[5] = fmaf(ev, wc.y, acc[5]);
                acc[6] = fmaf(ev, wc.z, acc[6]);
                acc[7] = fmaf(ev, wc.w, acc[7]);
            }
        }
        __syncthreads();                     // Eb reads done before T2 reuse

        // ---- D: log -> T2[b][cr] ----
        #pragma unroll
        for (int k = 0; k < 8; ++k)
            T2[b * 132 + (((ch << 3) + k) << 3) + r] = LN2 * __builtin_amdgcn_logf(acc[k]);
        __syncthreads();

        // ---- E: coalesced writeback ----
        #pragma unroll
        for (int i = 0; i < 2; ++i) {
            const int q  = i * 256 + t;
            const int bi = q >> 5, c0 = (q & 31) << 2;
            *(float4*)(out + (size_t)(b0 + bi) * 8192 + (f << 7) + c0) =
                *(const float4*)&T2[bi * 132 + c0];
        }
        __syncthreads();                     // T2 reads done before next iter's Eb writes
    }
}

extern "C" void kernel_launch(void* const* d_in, const int* in_sizes, int n_in,
                              void* d_out, int out_size, void* d_ws, size_t ws_size,
                              hipStream_t stream) {
    const float* ll     = (const float*)d_in[0];   // (256,64,32,8) f32
    const float* logits = (const float*)d_in[1];   // (64,32,16,8) f32
    float* out = (float*)d_out;                    // (256,64,16,8) f32

    fused_lse<<<dim3(1024), dim3(256), 0, stream>>>(ll, logits, out);
}

// Round 7
// 11.592 us; speedup vs baseline: 8.8529x; 8.8529x over previous
//
#include <hip/hip_runtime.h>
#include <cstdint>

// out[b,f,cout,r] = log( sum_cin exp(ll[b,f,cin,r]) * softmax_cin(logits)[f,cin,cout,r] )
// B=256, F=64, CIN=32, COUT=16, R=8
// Per (f, b-tile-16, r): D[16b][16cout] = E[16b][32cin] x W[32cin][16cout]
//   == one v_mfma_f32_16x16x32_bf16. Wave w handles r = {2w, 2w+1}.
#define LOG2E 1.4426950408889634f
#define LN2   0.6931471805599453f

typedef short short8 __attribute__((ext_vector_type(8)));
typedef float f32x4  __attribute__((ext_vector_type(4)));

static __device__ __forceinline__ short f2bf(float x) {
    union { float f; uint32_t u; } v; v.f = x;
    return (short)((v.u + 0x7FFFu + ((v.u >> 16) & 1u)) >> 16);   // RNE
}

// Grid = 1024 WGs (64 f x 16 b-tiles of 16), 256 threads (4 waves) => 4 WGs/CU.
// LDS (f32): Wb[8r][16cout][stride36], r-stride 584 (=8 mod 32: conflict-audited)
//            Eb[8r][16b ][stride36], r-stride 584; Eb reused as T2[16b][132] out tile.
// 9344 f32 = 36.5 KB -> 4 WGs/CU, 16 waves/CU.
__global__ __launch_bounds__(256) void fused_lse(const float* __restrict__ ll,
                                                 const float* __restrict__ logits,
                                                 float* __restrict__ out) {
    __shared__ float S[9344];
    float* Wb = S;
    float* Eb = S + 4672;
    float* T2 = S + 4672;                    // reuse after barrier 2

    const int t = threadIdx.x;
    const int w = t >> 6;                    // wave 0..3
    const int l = t & 63;

    // XCD-bijective swizzle: XCD x owns f in [x*8, x*8+8), all 16 b-tiles per f.
    const int bid = (int)blockIdx.x;
    const int swz = ((bid & 7) << 7) + (bid >> 3);
    const int f   = swz >> 4;
    const int b0  = (swz & 15) << 4;

    // ---- A1: cold ll loads first (4 x float4 per thread; one row of 256 per wave-j) ----
    float4 v[4];
    const float* llb = ll + (((size_t)b0 * 64 + f) << 8) + l * 4;
    #pragma unroll
    for (int j = 0; j < 4; ++j) {
        const int row = j * 4 + w;           // 0..15, wave-uniform
        v[j] = *(const float4*)(llb + ((size_t)row << 14));
    }

    // ---- A2: logits loads for softmax (threads 0..127; coalesced 512B/instr) ----
    float x[32];
    if (t < 128) {
        const float* lg = logits + ((size_t)f << 12) + t;    // t = cout*8 + r
        #pragma unroll
        for (int c = 0; c < 32; ++c) x[c] = lg[c << 7];
    }

    // ---- A3: exp(ll) -> Eb[r*584 + row*36 + cin]  (2-way banks: free) ----
    {
        const int cin = l >> 1;
        const int r0  = (l & 1) << 2;
        #pragma unroll
        for (int j = 0; j < 4; ++j) {
            float* eb = Eb + (j * 4 + w) * 36 + cin;
            eb[(r0 + 0) * 584] = __builtin_amdgcn_exp2f(v[j].x * LOG2E);
            eb[(r0 + 1) * 584] = __builtin_amdgcn_exp2f(v[j].y * LOG2E);
            eb[(r0 + 2) * 584] = __builtin_amdgcn_exp2f(v[j].z * LOG2E);
            eb[(r0 + 3) * 584] = __builtin_amdgcn_exp2f(v[j].w * LOG2E);
        }
    }

    // ---- A4: softmax over cin -> Wb[r*584 + cout*36 + cin] (float4 writes, 2-way) ----
    if (t < 128) {
        const int r_  = t & 7;
        const int co_ = t >> 3;
        float m = x[0];
        #pragma unroll
        for (int c = 1; c < 32; ++c) m = fmaxf(m, x[c]);
        float s = 0.f;
        #pragma unroll
        for (int c = 0; c < 32; ++c) { x[c] = __builtin_amdgcn_exp2f((x[c] - m) * LOG2E); s += x[c]; }
        const float inv = 1.0f / s;
        float* wrow = Wb + r_ * 584 + co_ * 36;
        #pragma unroll
        for (int q = 0; q < 8; ++q) {
            float4 y;
            y.x = x[q * 4 + 0] * inv; y.y = x[q * 4 + 1] * inv;
            y.z = x[q * 4 + 2] * inv; y.w = x[q * 4 + 3] * inv;
            *(float4*)&wrow[q * 4] = y;
        }
    }
    __syncthreads();

    // ---- C: two MFMAs per wave (r0=2w, r0+1) ----
    // A-frag: lane l holds E[r][m=l&15][k=(l>>4)*8 + j]; B-frag: W[r][k][n=l&15].
    // Same k-map for A and B -> any k-permutation cancels in the dot product.
    const int n   = l & 15;
    const int kg  = l >> 4;
    const int off = n * 36 + kg * 8;
    const int r0  = w << 1;
    const float* ea = Eb + r0 * 584 + off;
    const float* wa = Wb + r0 * 584 + off;

    float4 e0a = *(const float4*)ea,         e0b = *(const float4*)(ea + 4);
    float4 e1a = *(const float4*)(ea + 584), e1b = *(const float4*)(ea + 588);
    float4 w0a = *(const float4*)wa,         w0b = *(const float4*)(wa + 4);
    float4 w1a = *(const float4*)(wa + 584), w1b = *(const float4*)(wa + 588);

    short8 A0, A1, B0, B1;
#define PK8(D, P, Q) do { D[0]=f2bf(P.x); D[1]=f2bf(P.y); D[2]=f2bf(P.z); D[3]=f2bf(P.w); \
                          D[4]=f2bf(Q.x); D[5]=f2bf(Q.y); D[6]=f2bf(Q.z); D[7]=f2bf(Q.w); } while (0)
    PK8(A0, e0a, e0b); PK8(A1, e1a, e1b);
    PK8(B0, w0a, w0b); PK8(B1, w1a, w1b);
#undef PK8

    f32x4 acc0 = {0.f, 0.f, 0.f, 0.f};
    f32x4 acc1 = {0.f, 0.f, 0.f, 0.f};
    acc0 = __builtin_amdgcn_mfma_f32_16x16x32_bf16(A0, B0, acc0, 0, 0, 0);
    acc1 = __builtin_amdgcn_mfma_f32_16x16x32_bf16(A1, B1, acc1, 0, 0, 0);

    __syncthreads();                         // all Eb reads done before T2 reuse

    // ---- D: log; lane holds D[b=4*kg+i][cout=n] for r0,r0+1 -> float2 (r contiguous) ----
    #pragma unroll
    for (int i = 0; i < 4; ++i) {
        float2 g;
        g.x = LN2 * __builtin_amdgcn_logf(acc0[i]);
        g.y = LN2 * __builtin_amdgcn_logf(acc1[i]);
        const int bb = kg * 4 + i;
        *(float2*)&T2[bb * 132 + (n << 3) + r0] = g;
    }
    __syncthreads();

    // ---- E: coalesced writeback of [16b][128cr] tile ----
    #pragma unroll
    for (int i = 0; i < 2; ++i) {
        const int q  = i * 256 + t;
        const int bi = q >> 5, c0 = (q & 31) << 2;
        *(float4*)(out + (size_t)(b0 + bi) * 8192 + (f << 7) + c0) =
            *(const float4*)&T2[bi * 132 + c0];
    }
}

extern "C" void kernel_launch(void* const* d_in, const int* in_sizes, int n_in,
                              void* d_out, int out_size, void* d_ws, size_t ws_size,
                              hipStream_t stream) {
    const float* ll     = (const float*)d_in[0];   // (256,64,32,8) f32
    const float* logits = (const float*)d_in[1];   // (64,32,16,8) f32
    float* out = (float*)d_out;                    // (256,64,16,8) f32

    fused_lse<<<dim3(1024), dim3(256), 0, stream>>>(ll, logits, out);
}